// Round 1
// baseline (146.386 us; speedup 1.0000x reference)
//
#include <hip/hip_runtime.h>

// RotorQuantMSE: x[N,d] fp32, centroids[K] fp32, rotors[G,8] fp32
// out = concat(x_hat[N,d] f32, idx[N,d] stored-as-f32, norms[N] f32)
// Full fp64 pipeline to match the harness's np(float64) reference bit-for-bin.

// basis index -> blade bitmask; this permutation is an involution, so it is
// also the mask -> index map.
__device__ __constant__ int c_ORD[8] = {0, 1, 2, 4, 3, 5, 6, 7};

__device__ __forceinline__ double csign(int a, int b) {
    int s = 0, n = a >> 1;
    while (n) { s += __popc(n & b); n >>= 1; }
    return (s & 1) ? -1.0 : 1.0;
}

// Build per-group 3x3 forward map (rotor sandwich R v ~R restricted to the
// vector part) and 3x3 reconstruction map (sandwich with rotors*REV).
// mats[g*18 + 0..8]  = M_fwd row-major (out_k x in_m)
// mats[g*18 + 9..17] = M_rec row-major
__global__ void build_rotor_mats(const float* __restrict__ rotors,
                                 double* __restrict__ mats, int G) {
    int g = blockIdx.x * blockDim.x + threadIdx.x;
    if (g >= G) return;
    const double REV[8] = {1, 1, 1, 1, -1, -1, -1, -1};
    double R[8], Rr[8];
    for (int i = 0; i < 8; i++) {
        R[i]  = (double)rotors[g * 8 + i];
        Rr[i] = R[i] * REV[i];
    }
    double* out = mats + (size_t)g * 18;

    // pass 0: forward sandwich  t = R * e_m ; w = t * Rr
    // pass 1: recon sandwich    t = Rr * e_m ; w = t * R
    for (int pass = 0; pass < 2; pass++) {
        const double* L = pass ? Rr : R;   // left factor of first product
        const double* Q = pass ? R  : Rr;  // right factor of second product
        for (int m = 1; m <= 3; m++) {     // input basis vector e_m
            int am = c_ORD[m];
            double t[8];
            for (int i = 0; i < 8; i++) t[i] = 0.0;
            for (int p = 0; p < 8; p++) {
                int ap = c_ORD[p];
                t[c_ORD[ap ^ am]] += L[p] * csign(ap, am);
            }
            double wc[8];
            for (int i = 0; i < 8; i++) wc[i] = 0.0;
            for (int i = 0; i < 8; i++) {
                int ai = c_ORD[i];
                for (int j = 0; j < 8; j++) {
                    int aj = c_ORD[j];
                    wc[c_ORD[ai ^ aj]] += t[i] * Q[j] * csign(ai, aj);
                }
            }
            for (int k = 1; k <= 3; k++)
                out[pass * 9 + (k - 1) * 3 + (m - 1)] = wc[k];
        }
    }
}

// One block per row n; one thread per group g (blockDim.x == G, power of 2).
__global__ __launch_bounds__(256) void rotor_quant(
    const float* __restrict__ x, const float* __restrict__ cents,
    const double* __restrict__ mats,
    float* __restrict__ out_xhat, float* __restrict__ out_idx,
    float* __restrict__ out_norm, int G, int K) {
    const int n = blockIdx.x;
    const int tid = threadIdx.x;  // group id
    const int d = 3 * G;
    extern __shared__ char smem[];
    float*  xs  = (float*)smem;              // d floats: x row, later x_hat
    float*  qs  = xs + d;                    // d floats: idx as float
    double* red = (double*)(qs + d);         // blockDim doubles
    double* csd = red + blockDim.x;          // K doubles

    const float* xrow = x + (size_t)n * d;
    for (int i = tid; i < d; i += blockDim.x) xs[i] = xrow[i];
    if (tid < K) csd[tid] = (double)cents[tid];
    __syncthreads();

    // norm = sqrt(sum x^2) in fp64
    double ss = 0.0;
    for (int i = tid; i < d; i += blockDim.x) {
        double v = (double)xs[i];
        ss += v * v;
    }
    red[tid] = ss;
    __syncthreads();
    for (int off = blockDim.x >> 1; off > 0; off >>= 1) {
        if (tid < off) red[tid] += red[tid + off];
        __syncthreads();
    }
    double norm = sqrt(red[0]);
    if (norm < 1e-8) norm = 1e-8;

    // per-group rotate -> quantize -> unrotate (all fp64)
    const double* M = mats + (size_t)tid * 18;
    double u0 = (double)xs[3 * tid]     / norm;
    double u1 = (double)xs[3 * tid + 1] / norm;
    double u2 = (double)xs[3 * tid + 2] / norm;
    double w[3], v[3];
    int qi[3];
#pragma unroll
    for (int k = 0; k < 3; k++)
        w[k] = M[k * 3] * u0 + M[k * 3 + 1] * u1 + M[k * 3 + 2] * u2;
#pragma unroll
    for (int c = 0; c < 3; c++) {
        double best = 1e300;
        int bi = 0;
        for (int k = 0; k < K; k++) {           // first-wins: matches np.argmin
            double dd = fabs(w[c] - csd[k]);
            if (dd < best) { best = dd; bi = k; }
        }
        qi[c] = bi;
        v[c] = csd[bi];
    }
    double r[3];
#pragma unroll
    for (int k = 0; k < 3; k++)
        r[k] = M[9 + k * 3] * v[0] + M[9 + k * 3 + 1] * v[1] + M[9 + k * 3 + 2] * v[2];

    // safe to overwrite own 3 slots: all cross-thread reads of xs finished
    // before the reduction barriers above
    xs[3 * tid]     = (float)(r[0] * norm);
    xs[3 * tid + 1] = (float)(r[1] * norm);
    xs[3 * tid + 2] = (float)(r[2] * norm);
    qs[3 * tid]     = (float)qi[0];
    qs[3 * tid + 1] = (float)qi[1];
    qs[3 * tid + 2] = (float)qi[2];
    __syncthreads();

    float* oxh = out_xhat + (size_t)n * d;
    float* oix = out_idx + (size_t)n * d;
    for (int i = tid; i < d; i += blockDim.x) {
        oxh[i] = xs[i];
        oix[i] = qs[i];
    }
    if (tid == 0) out_norm[n] = (float)norm;
}

extern "C" void kernel_launch(void* const* d_in, const int* in_sizes, int n_in,
                              void* d_out, int out_size, void* d_ws, size_t ws_size,
                              hipStream_t stream) {
    const float* x      = (const float*)d_in[0];
    const float* cents  = (const float*)d_in[1];
    const float* rotors = (const float*)d_in[2];
    const int K = in_sizes[1];         // 16
    const int G = in_sizes[2] / 8;     // 256
    const int d = 3 * G;               // 768
    const int N = in_sizes[0] / d;     // 8192

    double* mats = (double*)d_ws;      // G*18 doubles = 36 KB

    build_rotor_mats<<<(G + 63) / 64, 64, 0, stream>>>(rotors, mats, G);

    float* out = (float*)d_out;
    float* out_xhat = out;
    float* out_idx  = out + (size_t)N * d;
    float* out_norm = out + (size_t)2 * N * d;
    size_t shmem = (size_t)(2 * d) * sizeof(float)
                 + (size_t)G * sizeof(double) + (size_t)K * sizeof(double);
    rotor_quant<<<N, G, shmem, stream>>>(x, cents, mats, out_xhat, out_idx,
                                         out_norm, G, K);
}

// Round 2
// 130.851 us; speedup vs baseline: 1.1187x; 1.1187x over previous
//
#include <hip/hip_runtime.h>

// RotorQuantMSE: x[N,d] fp32, centroids[K] fp32, rotors[G,8] fp32
// out = concat(x_hat[N,d] f32, idx[N,d] stored-as-f32, norms[N] f32)
//
// Strategy: per group g the rotor sandwich is a fixed 3x3 map. Forward map in
// fp64 (feeds the argmin decision -> must match np float64 ref bit-for-bin);
// reconstruction map in fp32 (idx exact => x_hat error ~1e-4 << 0.61 thr).
// Argmin over uniform linspace(-1,1,K): analytic candidate k0 =
// round((w+1)*(K-1)/2), then exact 3-candidate first-wins refine against the
// actual fp32-cast centroid values (midpoints differ from exact grid by ~5e-9).

__device__ __constant__ int c_ORD[8] = {0, 1, 2, 4, 3, 5, 6, 7};

__device__ __forceinline__ double csign(int a, int b) {
    int s = 0, n = a >> 1;
    while (n) { s += __popc(n & b); n >>= 1; }
    return (s & 1) ? -1.0 : 1.0;
}

// matsD[g*9 + (k-1)*3 + (m-1)] = fp64 forward sandwich 3x3 (R v ~R)
// matsF[g*9 + ...]             = fp32 recon sandwich 3x3  ((R*REV) v ~(R*REV))
__global__ void build_rotor_mats(const float* __restrict__ rotors,
                                 double* __restrict__ matsD,
                                 float* __restrict__ matsF, int G) {
    int g = blockIdx.x * blockDim.x + threadIdx.x;
    if (g >= G) return;
    const double REV[8] = {1, 1, 1, 1, -1, -1, -1, -1};
    double R[8], Rr[8];
    for (int i = 0; i < 8; i++) {
        R[i]  = (double)rotors[g * 8 + i];
        Rr[i] = R[i] * REV[i];
    }
    for (int pass = 0; pass < 2; pass++) {
        const double* L = pass ? Rr : R;   // left factor of first product
        const double* Q = pass ? R  : Rr;  // right factor of second product
        for (int m = 1; m <= 3; m++) {     // input basis vector e_m
            int am = c_ORD[m];
            double t[8];
            for (int i = 0; i < 8; i++) t[i] = 0.0;
            for (int p = 0; p < 8; p++) {
                int ap = c_ORD[p];
                t[c_ORD[ap ^ am]] += L[p] * csign(ap, am);
            }
            double wc[8];
            for (int i = 0; i < 8; i++) wc[i] = 0.0;
            for (int i = 0; i < 8; i++) {
                int ai = c_ORD[i];
                for (int j = 0; j < 8; j++) {
                    int aj = c_ORD[j];
                    wc[c_ORD[ai ^ aj]] += t[i] * Q[j] * csign(ai, aj);
                }
            }
            for (int k = 1; k <= 3; k++) {
                if (pass == 0)
                    matsD[(size_t)g * 9 + (k - 1) * 3 + (m - 1)] = wc[k];
                else
                    matsF[(size_t)g * 9 + (k - 1) * 3 + (m - 1)] = (float)wc[k];
            }
        }
    }
}

// One block per row n; one thread per group g (blockDim.x == G).
__global__ __launch_bounds__(256) void rotor_quant(
    const float* __restrict__ x, const float* __restrict__ cents,
    const double* __restrict__ matsD, const float* __restrict__ matsF,
    float* __restrict__ out_xhat, float* __restrict__ out_idx,
    float* __restrict__ out_norm, int G, int K) {
    const int n = blockIdx.x;
    const int tid = threadIdx.x;  // group id
    const int d = 3 * G;
    extern __shared__ char smem[];
    double* red = (double*)smem;             // 8 doubles: reduction + norm/inv
    double* csd = red + 8;                   // K doubles: fp64 centroids
    float*  csf = (float*)(csd + K);         // K floats:  fp32 centroids
    float*  xs  = csf + K;                   // d floats: x_hat staging
    float*  qs  = xs + d;                    // d floats: idx staging

    if (tid < K) {
        float c = cents[tid];
        csf[tid] = c;
        csd[tid] = (double)c;
    }

    // own 3 x values (wave covers a contiguous 768B span)
    const float* xrow = x + (size_t)n * d + 3 * tid;
    float xf0 = xrow[0], xf1 = xrow[1], xf2 = xrow[2];
    double x0 = (double)xf0, x1 = (double)xf1, x2 = (double)xf2;

    // block fp64 sum of squares: wave shuffle + tiny LDS combine
    double ss = x0 * x0 + x1 * x1 + x2 * x2;
    for (int off = 32; off > 0; off >>= 1) ss += __shfl_down(ss, off, 64);
    const int nwaves = blockDim.x >> 6;
    if ((tid & 63) == 0) red[tid >> 6] = ss;
    __syncthreads();
    if (tid == 0) {
        double tot = 0.0;
        for (int wv = 0; wv < nwaves; wv++) tot += red[wv];
        double nn = sqrt(tot);
        if (nn < 1e-8) nn = 1e-8;
        red[4] = nn;
        red[5] = 1.0 / nn;
    }
    __syncthreads();
    const double norm = red[4];
    const double inv  = red[5];

    // forward rotate in fp64: w = (M·x) * inv
    const double* M = matsD + (size_t)tid * 9;
    double w[3];
#pragma unroll
    for (int k = 0; k < 3; k++)
        w[k] = (M[k * 3] * x0 + M[k * 3 + 1] * x1 + M[k * 3 + 2] * x2) * inv;

    // quantize: analytic candidate + 3-way exact refine (first-wins == np.argmin)
    const double scale = 0.5 * (double)(K - 1);
    int qi[3];
    float v[3];
#pragma unroll
    for (int c = 0; c < 3; c++) {
        int k0 = (int)floor((w[c] + 1.0) * scale + 0.5);
        k0 = min(K - 1, max(0, k0));
        int ka = max(k0 - 1, 0);
        int kc = min(k0 + 1, K - 1);
        double best = fabs(w[c] - csd[ka]); int bi = ka;
        double db   = fabs(w[c] - csd[k0]); if (db < best) { best = db; bi = k0; }
        double dc   = fabs(w[c] - csd[kc]); if (dc < best) { best = dc; bi = kc; }
        qi[c] = bi;
        v[c] = csf[bi];
    }

    // reconstruction in fp32
    const float* Mr = matsF + (size_t)tid * 9;
    const float normf = (float)norm;
    float r[3];
#pragma unroll
    for (int k = 0; k < 3; k++)
        r[k] = (Mr[k * 3] * v[0] + Mr[k * 3 + 1] * v[1] + Mr[k * 3 + 2] * v[2]) * normf;

    xs[3 * tid]     = r[0];
    xs[3 * tid + 1] = r[1];
    xs[3 * tid + 2] = r[2];
    qs[3 * tid]     = (float)qi[0];
    qs[3 * tid + 1] = (float)qi[1];
    qs[3 * tid + 2] = (float)qi[2];
    __syncthreads();

    float* oxh = out_xhat + (size_t)n * d;
    float* oix = out_idx + (size_t)n * d;
    for (int i = tid; i < d; i += blockDim.x) {
        oxh[i] = xs[i];
        oix[i] = qs[i];
    }
    if (tid == 0) out_norm[n] = normf;
}

extern "C" void kernel_launch(void* const* d_in, const int* in_sizes, int n_in,
                              void* d_out, int out_size, void* d_ws, size_t ws_size,
                              hipStream_t stream) {
    const float* x      = (const float*)d_in[0];
    const float* cents  = (const float*)d_in[1];
    const float* rotors = (const float*)d_in[2];
    const int K = in_sizes[1];         // 16
    const int G = in_sizes[2] / 8;     // 256
    const int d = 3 * G;               // 768
    const int N = in_sizes[0] / d;     // 8192

    double* matsD = (double*)d_ws;                 // G*9 doubles = 18 KB
    float*  matsF = (float*)(matsD + (size_t)G * 9); // G*9 floats = 9 KB

    build_rotor_mats<<<(G + 63) / 64, 64, 0, stream>>>(rotors, matsD, matsF, G);

    float* out = (float*)d_out;
    float* out_xhat = out;
    float* out_idx  = out + (size_t)N * d;
    float* out_norm = out + (size_t)2 * N * d;
    size_t shmem = 8 * sizeof(double) + (size_t)K * (sizeof(double) + sizeof(float))
                 + (size_t)(2 * d) * sizeof(float);
    rotor_quant<<<N, G, shmem, stream>>>(x, cents, matsD, matsF, out_xhat,
                                         out_idx, out_norm, G, K);
}

// Round 3
// 113.795 us; speedup vs baseline: 1.2864x; 1.1499x over previous
//
#include <hip/hip_runtime.h>

// RotorQuantMSE: x[N,d] fp32, centroids[K] fp32, rotors[G,8] fp32
// out = concat(x_hat[N,d] f32, idx[N,d] stored-as-f32, norms[N] f32)
//
// Per group g the rotor sandwich is a fixed 3x3 map. Forward map fp64 (feeds
// the argmin decision -> matches np float64 ref), reconstruction fp32 (idx
// exact => x_hat error ~1e-4 << 0.61 threshold).
// Round 3: wave-per-row layout. Lane l owns groups 4l..4l+3 (12 contiguous
// floats -> 3x float4). Norm via shfl_xor butterfly; no block barriers in the
// hot path; direct float4 stores. Argmin via analytic candidate + exact fp64
// midpoint refine (first-wins == np.argmin: pick k over k+1 iff w <= mid_k).

__device__ __constant__ int c_ORD[8] = {0, 1, 2, 4, 3, 5, 6, 7};

__device__ __forceinline__ double csign(int a, int b) {
    int s = 0, n = a >> 1;
    while (n) { s += __popc(n & b); n >>= 1; }
    return (s & 1) ? -1.0 : 1.0;
}

// One thread per (g, pass, m): computes one column of one 3x3 sandwich matrix.
// matsD[g*9 + (k-1)*3 + (m-1)] = fp64 forward (R v ~R)
// matsF[g*9 + ...]             = fp32 recon   ((R*REV) v ~(R*REV))
__global__ void build_rotor_mats(const float* __restrict__ rotors,
                                 double* __restrict__ matsD,
                                 float* __restrict__ matsF, int G) {
    int t = blockIdx.x * blockDim.x + threadIdx.x;
    if (t >= G * 6) return;
    const int g = t / 6;
    const int rem = t % 6;
    const int pass = rem / 3;      // 0 = forward, 1 = recon
    const int m = rem % 3 + 1;     // input basis vector e_m
    const double REV[8] = {1, 1, 1, 1, -1, -1, -1, -1};
    double R[8], Rr[8];
    for (int i = 0; i < 8; i++) {
        R[i]  = (double)rotors[g * 8 + i];
        Rr[i] = R[i] * REV[i];
    }
    const double* L = pass ? Rr : R;   // left factor of first product
    const double* Q = pass ? R  : Rr;  // right factor of second product
    const int am = c_ORD[m];
    double tv[8];
    for (int i = 0; i < 8; i++) tv[i] = 0.0;
    for (int p = 0; p < 8; p++) {
        int ap = c_ORD[p];
        tv[c_ORD[ap ^ am]] += L[p] * csign(ap, am);
    }
    double wc[8];
    for (int i = 0; i < 8; i++) wc[i] = 0.0;
    for (int i = 0; i < 8; i++) {
        int ai = c_ORD[i];
        for (int j = 0; j < 8; j++) {
            int aj = c_ORD[j];
            wc[c_ORD[ai ^ aj]] += tv[i] * Q[j] * csign(ai, aj);
        }
    }
    for (int k = 1; k <= 3; k++) {
        if (pass == 0)
            matsD[(size_t)g * 9 + (k - 1) * 3 + (m - 1)] = wc[k];
        else
            matsF[(size_t)g * 9 + (k - 1) * 3 + (m - 1)] = (float)wc[k];
    }
}

// 256 threads = 4 waves; one wave per row. Lane l: groups 4l..4l+3.
__global__ __launch_bounds__(256, 4) void rotor_quant(
    const float* __restrict__ x, const float* __restrict__ cents,
    const double* __restrict__ matsD, const float* __restrict__ matsF,
    float* __restrict__ out_xhat, float* __restrict__ out_idx,
    float* __restrict__ out_norm, int N, int G, int K) {
    const int tid = threadIdx.x;
    const int lane = tid & 63;
    const int wid = tid >> 6;
    const int n = blockIdx.x * 4 + wid;
    const int d = 3 * G;

    __shared__ float csf[16];    // fp32 centroid values (dequant table)
    __shared__ double mid[15];   // exact fp64 midpoints (argmin boundaries)
    if (tid < K) csf[tid] = cents[tid];
    if (tid < K - 1)
        mid[tid] = 0.5 * ((double)cents[tid] + (double)cents[tid + 1]);
    __syncthreads();
    if (n >= N) return;

    // load 12 contiguous floats (3x float4, 48B-aligned per lane)
    const float4* xrow = (const float4*)(x + (size_t)n * d) + lane * 3;
    float4 xa = xrow[0], xb = xrow[1], xc = xrow[2];
    float xf[12] = {xa.x, xa.y, xa.z, xa.w, xb.x, xb.y, xb.z, xb.w,
                    xc.x, xc.y, xc.z, xc.w};

    // fp64 sum of squares + wave butterfly (all lanes end with the total)
    double ss = 0.0;
#pragma unroll
    for (int i = 0; i < 12; i++) {
        double v = (double)xf[i];
        ss += v * v;
    }
#pragma unroll
    for (int off = 32; off > 0; off >>= 1) ss += __shfl_xor(ss, off, 64);
    double nn = sqrt(ss);
    if (nn < 1e-8) nn = 1e-8;
    const double inv = 1.0 / nn;
    const float normf = (float)nn;

    const double scale = 0.5 * (double)(K - 1);
    float oh[12], oq[12];
#pragma unroll
    for (int j = 0; j < 4; j++) {
        const int g = 4 * lane + j;
        const double* M = matsD + (size_t)g * 9;
        const double x0 = (double)xf[3 * j], x1 = (double)xf[3 * j + 1],
                     x2 = (double)xf[3 * j + 2];
        double w[3];
#pragma unroll
        for (int k = 0; k < 3; k++)
            w[k] = (M[3 * k] * x0 + M[3 * k + 1] * x1 + M[3 * k + 2] * x2) * inv;

        int qi[3];
        float v[3];
#pragma unroll
        for (int c = 0; c < 3; c++) {
            int i = (int)((w[c] + 1.0) * scale + 0.5);   // trunc; w+1 >= ~0
            i = min(K - 1, max(0, i));
            // first-wins nearest: prefer k over k+1 iff w <= mid_k
            if (i > 0 && w[c] <= mid[i - 1]) i -= 1;
            else if (i < K - 1 && w[c] > mid[i]) i += 1;
            qi[c] = i;
            v[c] = csf[i];
        }

        const float* Mr = matsF + (size_t)g * 9;
        oh[3 * j]     = (Mr[0] * v[0] + Mr[1] * v[1] + Mr[2] * v[2]) * normf;
        oh[3 * j + 1] = (Mr[3] * v[0] + Mr[4] * v[1] + Mr[5] * v[2]) * normf;
        oh[3 * j + 2] = (Mr[6] * v[0] + Mr[7] * v[1] + Mr[8] * v[2]) * normf;
        oq[3 * j]     = (float)qi[0];
        oq[3 * j + 1] = (float)qi[1];
        oq[3 * j + 2] = (float)qi[2];
    }

    float4* oxh = (float4*)(out_xhat + (size_t)n * d) + lane * 3;
    float4* oix = (float4*)(out_idx + (size_t)n * d) + lane * 3;
    oxh[0] = make_float4(oh[0], oh[1], oh[2], oh[3]);
    oxh[1] = make_float4(oh[4], oh[5], oh[6], oh[7]);
    oxh[2] = make_float4(oh[8], oh[9], oh[10], oh[11]);
    oix[0] = make_float4(oq[0], oq[1], oq[2], oq[3]);
    oix[1] = make_float4(oq[4], oq[5], oq[6], oq[7]);
    oix[2] = make_float4(oq[8], oq[9], oq[10], oq[11]);
    if (lane == 0) out_norm[n] = normf;
}

extern "C" void kernel_launch(void* const* d_in, const int* in_sizes, int n_in,
                              void* d_out, int out_size, void* d_ws, size_t ws_size,
                              hipStream_t stream) {
    const float* x      = (const float*)d_in[0];
    const float* cents  = (const float*)d_in[1];
    const float* rotors = (const float*)d_in[2];
    const int K = in_sizes[1];         // 16
    const int G = in_sizes[2] / 8;     // 256
    const int d = 3 * G;               // 768
    const int N = in_sizes[0] / d;     // 8192

    double* matsD = (double*)d_ws;                   // G*9 doubles = 18 KB
    float*  matsF = (float*)(matsD + (size_t)G * 9); // G*9 floats  =  9 KB

    build_rotor_mats<<<(G * 6 + 255) / 256, 256, 0, stream>>>(rotors, matsD,
                                                              matsF, G);

    float* out = (float*)d_out;
    float* out_xhat = out;
    float* out_idx  = out + (size_t)N * d;
    float* out_norm = out + (size_t)2 * N * d;
    rotor_quant<<<(N + 3) / 4, 256, 0, stream>>>(x, cents, matsD, matsF,
                                                 out_xhat, out_idx, out_norm,
                                                 N, G, K);
}

// Round 4
// 99.106 us; speedup vs baseline: 1.4771x; 1.1482x over previous
//
#include <hip/hip_runtime.h>

// RotorQuantMSE: x[N,d] fp32, centroids[K] fp32, rotors[G,8] fp32
// out = concat(x_hat[N,d] f32, idx[N,d] stored-as-f32, norms[N] f32)
//
// Round 4: single fused kernel. The rotor sandwich R v ~R restricted to
// vectors has the closed form (R = a + p e12 + q e13 + r e23; components
// 1,2,3,7 of the input rotors are exactly zero by construction):
//   M_fwd = [ a^2-p^2-q^2+r^2   2(ap-qr)          2(aq+pr)        ]
//           [ -2(ap+qr)         a^2-p^2+q^2-r^2   2(ar-pq)        ]
//           [ 2(pr-aq)          -2(ar+pq)         a^2+p^2-q^2-r^2 ]
// and the reconstruction sandwich (with R*REV) is exactly M_fwd^T (verified
// symbolically vs the Cayley-table build used in rounds 1-3, which passed).
// Forward map in fp64 (feeds argmin -> matches np float64 ref); recon in fp32
// (idx exact => x_hat error ~1e-4 << 0.61 threshold).
// Wave-per-row: lane l owns groups 4l..4l+3 (12 contiguous floats = 3x
// float4); butterfly norm; midpoint-rule argmin (first-wins == np.argmin);
// direct float4 stores.

__global__ __launch_bounds__(256, 4) void rotor_quant(
    const float* __restrict__ x, const float* __restrict__ cents,
    const float* __restrict__ rotors,
    float* __restrict__ out_xhat, float* __restrict__ out_idx,
    float* __restrict__ out_norm, int N, int G, int K) {
    const int tid = threadIdx.x;
    const int lane = tid & 63;
    const int wid = tid >> 6;
    const int n = blockIdx.x * 4 + wid;
    const int d = 3 * G;

    __shared__ float csf[16];    // fp32 centroid values (dequant table)
    __shared__ double mid[15];   // exact fp64 midpoints (argmin boundaries)
    if (tid < K) csf[tid] = cents[tid];
    if (tid < K - 1)
        mid[tid] = 0.5 * ((double)cents[tid] + (double)cents[tid + 1]);
    __syncthreads();
    if (n >= N) return;

    // load 12 contiguous x floats (3x float4 per lane)
    const float4* xrow = (const float4*)(x + (size_t)n * d) + lane * 3;
    float4 xa = xrow[0], xb = xrow[1], xc = xrow[2];
    float xf[12] = {xa.x, xa.y, xa.z, xa.w, xb.x, xb.y, xb.z, xb.w,
                    xc.x, xc.y, xc.z, xc.w};

    // fp64 sum of squares + wave butterfly (all lanes end with the total)
    double ss = 0.0;
#pragma unroll
    for (int i = 0; i < 12; i++) {
        double v = (double)xf[i];
        ss += v * v;
    }
#pragma unroll
    for (int off = 32; off > 0; off >>= 1) ss += __shfl_xor(ss, off, 64);
    double nn = sqrt(ss);
    if (nn < 1e-8) nn = 1e-8;
    const double inv = 1.0 / nn;
    const float normf = (float)nn;

    const double scale = 0.5 * (double)(K - 1);
    const float4* rot4 = (const float4*)rotors;
    float oh[12], oq[12];
#pragma unroll
    for (int j = 0; j < 4; j++) {
        const int g = 4 * lane + j;
        // rotor components: [0]=scalar a, [4]=p(e12), [5]=q(e13), [6]=r(e23)
        float4 r0 = rot4[2 * g];
        float4 r1 = rot4[2 * g + 1];
        const double A = (double)r0.x, P = (double)r1.x,
                     Q = (double)r1.y, R = (double)r1.z;
        const double aa = A * A, pp = P * P, qq = Q * Q, rr = R * R;
        const double ap = A * P, aq = A * Q, ar = A * R;
        const double pq = P * Q, pr = P * R, qr = Q * R;
        const double m00 = aa - pp - qq + rr;
        const double m01 = 2.0 * (ap - qr);
        const double m02 = 2.0 * (aq + pr);
        const double m10 = -2.0 * (ap + qr);
        const double m11 = aa - pp + qq - rr;
        const double m12 = 2.0 * (ar - pq);
        const double m20 = 2.0 * (pr - aq);
        const double m21 = -2.0 * (ar + pq);
        const double m22 = aa + pp - qq - rr;

        const double x0 = (double)xf[3 * j], x1 = (double)xf[3 * j + 1],
                     x2 = (double)xf[3 * j + 2];
        double w[3];
        w[0] = (m00 * x0 + m01 * x1 + m02 * x2) * inv;
        w[1] = (m10 * x0 + m11 * x1 + m12 * x2) * inv;
        w[2] = (m20 * x0 + m21 * x1 + m22 * x2) * inv;

        int qi[3];
        float v[3];
#pragma unroll
        for (int c = 0; c < 3; c++) {
            int i = (int)((w[c] + 1.0) * scale + 0.5);   // trunc; w+1 >= ~0
            i = min(K - 1, max(0, i));
            // first-wins nearest: prefer k over k+1 iff w <= mid_k
            if (i > 0 && w[c] <= mid[i - 1]) i -= 1;
            else if (i < K - 1 && w[c] > mid[i]) i += 1;
            qi[c] = i;
            v[c] = csf[i];
        }

        // reconstruction sandwich = M_fwd^T, applied in fp32
        const float f00 = (float)m00, f01 = (float)m01, f02 = (float)m02;
        const float f10 = (float)m10, f11 = (float)m11, f12 = (float)m12;
        const float f20 = (float)m20, f21 = (float)m21, f22 = (float)m22;
        oh[3 * j]     = (f00 * v[0] + f10 * v[1] + f20 * v[2]) * normf;
        oh[3 * j + 1] = (f01 * v[0] + f11 * v[1] + f21 * v[2]) * normf;
        oh[3 * j + 2] = (f02 * v[0] + f12 * v[1] + f22 * v[2]) * normf;
        oq[3 * j]     = (float)qi[0];
        oq[3 * j + 1] = (float)qi[1];
        oq[3 * j + 2] = (float)qi[2];
    }

    float4* oxh = (float4*)(out_xhat + (size_t)n * d) + lane * 3;
    float4* oix = (float4*)(out_idx + (size_t)n * d) + lane * 3;
    oxh[0] = make_float4(oh[0], oh[1], oh[2], oh[3]);
    oxh[1] = make_float4(oh[4], oh[5], oh[6], oh[7]);
    oxh[2] = make_float4(oh[8], oh[9], oh[10], oh[11]);
    oix[0] = make_float4(oq[0], oq[1], oq[2], oq[3]);
    oix[1] = make_float4(oq[4], oq[5], oq[6], oq[7]);
    oix[2] = make_float4(oq[8], oq[9], oq[10], oq[11]);
    if (lane == 0) out_norm[n] = normf;
}

extern "C" void kernel_launch(void* const* d_in, const int* in_sizes, int n_in,
                              void* d_out, int out_size, void* d_ws, size_t ws_size,
                              hipStream_t stream) {
    const float* x      = (const float*)d_in[0];
    const float* cents  = (const float*)d_in[1];
    const float* rotors = (const float*)d_in[2];
    const int K = in_sizes[1];         // 16
    const int G = in_sizes[2] / 8;     // 256
    const int d = 3 * G;               // 768
    const int N = in_sizes[0] / d;     // 8192

    float* out = (float*)d_out;
    float* out_xhat = out;
    float* out_idx  = out + (size_t)N * d;
    float* out_norm = out + (size_t)2 * N * d;
    rotor_quant<<<(N + 3) / 4, 256, 0, stream>>>(x, cents, rotors, out_xhat,
                                                 out_idx, out_norm, N, G, K);
}